// Round 16
// baseline (1159.292 us; speedup 1.0000x reference)
//
#include <hip/hip_runtime.h>
#include <stdint.h>

#define N_NODES 100000
#define F_DIM   500
#define C_DIM   40
#define H_DIM   256
#define HX_DIM  64
#define O_DIM   320   // H + HX
#define E_NUM   1600000
#define RH_LD   328
#define BN      320

typedef unsigned short u16;
typedef unsigned int   u32;
typedef __attribute__((ext_vector_type(4))) u16    u16x4;
typedef __attribute__((ext_vector_type(8))) u16    u16x8;
typedef __attribute__((ext_vector_type(4))) float  f32x4;
typedef __attribute__((ext_vector_type(8))) short  bf16x8;  // MFMA A/B frag

__device__ __forceinline__ float bf2f(u16 v) {
  u32 u = ((u32)v) << 16;
  return __builtin_bit_cast(float, u);
}
__device__ __forceinline__ u16 f2bf(float f) {   // round-to-nearest-even
  u32 x = __builtin_bit_cast(u32, f);
  x += 0x7fffu + ((x >> 16) & 1u);
  return (u16)(x >> 16);
}

// ---------------- Kernel 0: train_mask encoding detector ----------------
__global__ __launch_bounds__(256) void k_detect(const u32* __restrict__ tm, int* __restrict__ flag)
{
  __shared__ int s;
  if (threadIdx.x == 0) s = 0;
  __syncthreads();
  int local = 0;
  #pragma unroll
  for (int j = 0; j < 16; ++j) {
    if (tm[j * 256 + threadIdx.x] > 1u) local = 1;
  }
  if (local) s = 1;
  __syncthreads();
  if (threadIdx.x == 0) *flag = s;
}

// ---------------- Kernel 0b: W=[fc1_w;xenc_w] -> bf16, K-chunked frag layout ----------------
__global__ __launch_bounds__(256) void k_cvtw(
    const float* __restrict__ fc1w, const float* __restrict__ xencw, u16* __restrict__ wws)
{
  const int g = blockIdx.x * 256 + threadIdx.x;   // 20480 groups
  const int c = g / 1280;
  const int rem = g - c * 1280;
  const int r = rem >> 2;
  const int k0 = c * 32 + (rem & 3) * 8;
  const float* src = (r < H_DIM) ? (fc1w + (long)r * F_DIM)
                                 : (xencw + (long)(r - H_DIM) * F_DIM);
  f32x4 v0 = {0.f, 0.f, 0.f, 0.f}, v1 = v0;
  if (k0 + 4 <= F_DIM) v0 = *(const f32x4*)(src + k0);
  if (k0 + 8 <= F_DIM) v1 = *(const f32x4*)(src + k0 + 4);
  u16x8 o;
  #pragma unroll
  for (int i = 0; i < 4; ++i) { o[i] = f2bf(v0[i]); o[4 + i] = f2bf(v1[i]); }
  *(u16x8*)(wws + (size_t)g * 8) = o;
}

// ---------------- Kernel 0c: B' (48 x 320) -> bf16 K-chunked frag layout ----------------
__global__ __launch_bounds__(256) void k_cvtw2(
    const float* __restrict__ fc2w, const float* __restrict__ pw, u16* __restrict__ wwsB)
{
  const int g = blockIdx.x * 256 + threadIdx.x;   // 1920 groups
  if (g >= 1920) return;
  const int kc = g / 192;
  const int rem = g - kc * 192;
  const int r = rem >> 2;
  const int k0 = kc * 32 + (rem & 3) * 8;
  const float* src = nullptr;
  if (r < C_DIM)           { if (k0 + 8 <= H_DIM) src = fc2w + r * H_DIM + k0; }
  else if (r == C_DIM)     { if (k0 >= H_DIM) src = pw + (k0 - H_DIM); }
  else if (r == C_DIM + 1) { if (k0 >= H_DIM) src = pw + HX_DIM + (k0 - H_DIM); }
  u16x8 o = {0, 0, 0, 0, 0, 0, 0, 0};
  if (src) {
    const f32x4 v0 = *(const f32x4*)src;
    const f32x4 v1 = *(const f32x4*)(src + 4);
    #pragma unroll
    for (int i = 0; i < 4; ++i) { o[i] = f2bf(v0[i]); o[4 + i] = f2bf(v1[i]); }
  }
  *(u16x8*)(wwsB + (size_t)g * 8) = o;
}

// ---------------- Kernel 0d: x -> bf16, frag-ready K-chunked layout ----------------
__global__ __launch_bounds__(256) void k_cvtx(
    const float* __restrict__ x, u16* __restrict__ xbf)
{
  const int b = blockIdx.x;            // 3125
  const int t = threadIdx.x;
  const int r = t >> 3, q = t & 7;
  const long row = (long)b * 32 + r;
  const float* xr = x + row * F_DIM;
  u16* dst = xbf + ((size_t)b * 16) * 1024 + r * 32 + q * 4;
  #pragma unroll
  for (int kc = 0; kc < 16; ++kc) {
    const int k0 = kc * 32 + q * 4;
    f32x4 v = {0.f, 0.f, 0.f, 0.f};
    if (k0 + 4 <= F_DIM) v = *(const f32x4*)(xr + k0);
    u16x4 o;
    #pragma unroll
    for (int i = 0; i < 4; ++i) o[i] = f2bf(v[i]);
    *(u16x4*)(dst + kc * 1024) = o;
  }
}

// ---------------- shared phase-2 pieces (validated r4-r15 math) ----------------
__device__ __forceinline__ void epilogue_store(
    u16* sOut, f32x4 (&acc)[2][5], const float* __restrict__ fc1b,
    const float* __restrict__ xencb, int wcol, int l15, int lgrp)
{
  #pragma unroll
  for (int n = 0; n < 5; ++n) {
    const int col = wcol * 80 + n * 16 + l15;
    const float bias = (col < H_DIM) ? fc1b[col] : xencb[col - H_DIM];
    #pragma unroll
    for (int m = 0; m < 2; ++m) {
      const int r0 = m * 16 + lgrp * 4;
      #pragma unroll
      for (int rg = 0; rg < 4; ++rg)
        sOut[(r0 + rg) * RH_LD + col] = f2bf(fmaxf(acc[m][n][rg] + bias, 0.f));
    }
  }
}

__device__ __forceinline__ void rowhead_phase2(
    const u16* __restrict__ sOut, const u16* __restrict__ wwsB,
    const int* __restrict__ y, const void* __restrict__ tmask,
    const float* __restrict__ fc2b, const float* __restrict__ pw,
    bool byte_mask, long rowbase, int tid,
    float* __restrict__ out_lp, float* __restrict__ sq_out, float* __restrict__ sk_out)
{
  if (tid >= 128) return;
  const int lane = tid & 63, wid = tid >> 6;   // 0..1
  const int l15 = lane & 15, lgrp = lane >> 4;
  const u16* bBase = wwsB + l15 * 32 + lgrp * 8;
  f32x4 racc[3];
  #pragma unroll
  for (int n = 0; n < 3; ++n) racc[n] = (f32x4){0.f, 0.f, 0.f, 0.f};
  const u16* pa = sOut + (wid * 16 + l15) * RH_LD + lgrp * 8;

  bf16x8 bc[3], bn[3];
  #pragma unroll
  for (int n = 0; n < 3; ++n) bc[n] = *(const bf16x8*)(bBase + n * 512);

#define RH(kc, BC, BN_)                                                        \
  {                                                                            \
    if ((kc) < 9) {                                                            \
      _Pragma("unroll")                                                        \
      for (int n = 0; n < 3; ++n)                                              \
        BN_[n] = *(const bf16x8*)(bBase + ((kc) + 1) * 1536 + n * 512);        \
    }                                                                          \
    const bf16x8 a = *(const bf16x8*)(pa + (kc) * 32);                         \
    _Pragma("unroll")                                                          \
    for (int n = 0; n < 3; ++n)                                                \
      racc[n] = __builtin_amdgcn_mfma_f32_16x16x32_bf16(a, BC[n], racc[n], 0, 0, 0); \
  }
  RH(0, bc, bn) RH(1, bn, bc) RH(2, bc, bn) RH(3, bn, bc) RH(4, bc, bn)
  RH(5, bn, bc) RH(6, bc, bn) RH(7, bn, bc) RH(8, bc, bn) RH(9, bn, bc)
#undef RH

  const int c0 = l15, c1 = 16 + l15, c2 = 32 + l15;
  const bool v2 = (l15 < 8);
  const float b0 = fc2b[c0], b1 = fc2b[c1], b2 = v2 ? fc2b[c2] : 0.f;
  const float wq0 = pw[2 * HX_DIM + c0], wq1 = pw[2 * HX_DIM + c1],
              wq2 = v2 ? pw[2 * HX_DIM + c2] : 0.f;
  const float wk0 = pw[2 * HX_DIM + C_DIM + c0], wk1 = pw[2 * HX_DIM + C_DIM + c1],
              wk2 = v2 ? pw[2 * HX_DIM + C_DIM + c2] : 0.f;

  #pragma unroll
  for (int rg = 0; rg < 4; ++rg) {
    const long row = rowbase + wid * 16 + lgrp * 4 + rg;
    const float lg0 = racc[0][rg] + b0;
    const float lg1 = racc[1][rg] + b1;
    const float lg2 = racc[2][rg] + b2;
    const float sxq = __shfl(racc[2][rg], (lane & 48) | 8, 64);   // col 40: xe.w_xq
    const float sxk = __shfl(racc[2][rg], (lane & 48) | 9, 64);   // col 41: xe.w_xk

    float m = fmaxf(lg0, lg1);
    if (v2) m = fmaxf(m, lg2);
    #pragma unroll
    for (int off = 1; off < 16; off <<= 1) m = fmaxf(m, __shfl_xor(m, off, 64));
    const float e0 = __expf(lg0 - m), e1 = __expf(lg1 - m),
                e2 = v2 ? __expf(lg2 - m) : 0.f;
    float s = e0 + e1 + e2;
    #pragma unroll
    for (int off = 1; off < 16; off <<= 1) s += __shfl_xor(s, off, 64);
    const float lse = m + __logf(s);
    const float inv = 1.f / s;

    const int yv = y[row];
    const bool tm = byte_mask ? (((const unsigned char*)tmask)[row] != 0)
                              : (((const int*)tmask)[row] != 0);
    const float p0 = tm ? (c0 == yv ? 1.f : 0.f) : e0 * inv;
    const float p1 = tm ? (c1 == yv ? 1.f : 0.f) : e1 * inv;
    const float p2 = tm ? (c2 == yv ? 1.f : 0.f) : e2 * inv;
    float sq = p0 * wq0 + p1 * wq1 + p2 * wq2;
    float sk = p0 * wk0 + p1 * wk1 + p2 * wk2;
    #pragma unroll
    for (int off = 1; off < 16; off <<= 1) {
      sq += __shfl_xor(sq, off, 64);
      sk += __shfl_xor(sk, off, 64);
    }

    float* lp = out_lp + row * C_DIM;
    lp[c0] = lg0 - lse;
    lp[c1] = lg1 - lse;
    if (v2) lp[c2] = lg2 - lse;
    if (l15 == 0) { sq_out[row] = sq + sxq; sk_out[row] = sk + sxk; }
  }
}

// ---------------- Kernel 1a: FUSED direct-A (r15, unchanged, REAL output) ----------------
__global__ __launch_bounds__(256, 4) void k_fused_d(
    const u16* __restrict__ xbf, const u16* __restrict__ wws, const u16* __restrict__ wwsB,
    const float* __restrict__ fc1b, const float* __restrict__ xencb,
    const int* __restrict__ y, const void* __restrict__ tmask,
    const float* __restrict__ fc2b, const float* __restrict__ pw,
    const int* __restrict__ mask_flag,
    float* __restrict__ out_lp, float* __restrict__ sq_out, float* __restrict__ sk_out)
{
  __shared__ __align__(16) u16 sOut[32 * RH_LD];

  const int tid  = threadIdx.x;
  const int lane = tid & 63;
  const int wcol = tid >> 6;
  const int l15 = lane & 15, lgrp = lane >> 4;
  const long rowbase = (long)blockIdx.x * 32;

  const u16* abase = xbf + (size_t)blockIdx.x * 16384 + l15 * 32 + lgrp * 8;
  const u16* bbase = wws + (wcol * 80 + l15) * 32 + lgrp * 8;

  f32x4 acc[2][5];
  #pragma unroll
  for (int m = 0; m < 2; ++m)
    #pragma unroll
    for (int n = 0; n < 5; ++n)
      acc[m][n] = (f32x4){0.f, 0.f, 0.f, 0.f};

#define LAD(A0, A1, kc)                                                        \
  {                                                                            \
    A0 = *(const bf16x8*)(abase + (kc) * 1024);                                \
    A1 = *(const bf16x8*)(abase + (kc) * 1024 + 512);                          \
  }
#define LB(dst, kc)                                                            \
  {                                                                            \
    const u16* bp = bbase + (size_t)(kc) * (BN * 32);                          \
    _Pragma("unroll")                                                          \
    for (int n = 0; n < 5; ++n) dst[n] = *(const bf16x8*)(bp + n * 512);       \
  }
#define GS(kc, AC0, AC1, AN0, AN1, BU, BL)                                     \
  {                                                                            \
    if ((kc) < 15) { LAD(AN0, AN1, (kc) + 1); LB(BL, (kc) + 1); }              \
    _Pragma("unroll")                                                          \
    for (int n = 0; n < 5; ++n) {                                              \
      acc[0][n] = __builtin_amdgcn_mfma_f32_16x16x32_bf16(AC0, BU[n], acc[0][n], 0, 0, 0); \
      acc[1][n] = __builtin_amdgcn_mfma_f32_16x16x32_bf16(AC1, BU[n], acc[1][n], 0, 0, 0); \
    }                                                                          \
  }

  bf16x8 aX0, aX1, aY0, aY1, bP[5], bQ[5];
  LAD(aX0, aX1, 0); LB(bP, 0);
  GS(0,  aX0, aX1, aY0, aY1, bP, bQ)  GS(1,  aY0, aY1, aX0, aX1, bQ, bP)
  GS(2,  aX0, aX1, aY0, aY1, bP, bQ)  GS(3,  aY0, aY1, aX0, aX1, bQ, bP)
  GS(4,  aX0, aX1, aY0, aY1, bP, bQ)  GS(5,  aY0, aY1, aX0, aX1, bQ, bP)
  GS(6,  aX0, aX1, aY0, aY1, bP, bQ)  GS(7,  aY0, aY1, aX0, aX1, bQ, bP)
  GS(8,  aX0, aX1, aY0, aY1, bP, bQ)  GS(9,  aY0, aY1, aX0, aX1, bQ, bP)
  GS(10, aX0, aX1, aY0, aY1, bP, bQ)  GS(11, aY0, aY1, aX0, aX1, bQ, bP)
  GS(12, aX0, aX1, aY0, aY1, bP, bQ)  GS(13, aY0, aY1, aX0, aX1, bQ, bP)
  GS(14, aX0, aX1, aY0, aY1, bP, bQ)  GS(15, aY0, aY1, aX0, aX1, bQ, bP)
#undef LAD
#undef LB
#undef GS

  epilogue_store(sOut, acc, fc1b, xencb, wcol, l15, lgrp);
  __syncthreads();
  rowhead_phase2(sOut, wwsB, y, tmask, fc2b, pw, (*mask_flag != 0), rowbase, tid,
                 out_lp, sq_out, sk_out);
}

// ================= PROBES (4x grid, clones via bid%3125, scratch ring) =================

// ---- k_p_ld: load path ONLY (A+B), no MFMA, no phase 2 ----
__global__ __launch_bounds__(256, 4) void k_p_ld(
    const u16* __restrict__ xbf, const u16* __restrict__ wws, float* __restrict__ ring)
{
  const int tid  = threadIdx.x;
  const int lane = tid & 63;
  const int wcol = tid >> 6;
  const int l15 = lane & 15, lgrp = lane >> 4;
  const u32 bid = blockIdx.x % 3125u;

  const u16* abase = xbf + (size_t)bid * 16384 + l15 * 32 + lgrp * 8;
  const u16* bbase = wws + (wcol * 80 + l15) * 32 + lgrp * 8;

  float keep = 0.f;
  #pragma unroll
  for (int kc = 0; kc < 16; ++kc) {
    const bf16x8 a0 = *(const bf16x8*)(abase + kc * 1024);
    const bf16x8 a1 = *(const bf16x8*)(abase + kc * 1024 + 512);
    keep += bf2f((u16)a0[0]) + bf2f((u16)a1[0]);
    const u16* bp = bbase + (size_t)kc * (BN * 32);
    #pragma unroll
    for (int n = 0; n < 5; ++n) {
      const bf16x8 b = *(const bf16x8*)(bp + n * 512);
      keep += bf2f((u16)b[0]);
    }
  }
  ring[(blockIdx.x * 256 + tid) & 16383] = keep;   // racy scratch; never read
}

// ---- k_p_mf: MFMA ONLY (frags loaded once), no per-step loads, no phase 2 ----
__global__ __launch_bounds__(256, 4) void k_p_mf(
    const u16* __restrict__ xbf, const u16* __restrict__ wws, float* __restrict__ ring)
{
  const int tid  = threadIdx.x;
  const int lane = tid & 63;
  const int wcol = tid >> 6;
  const int l15 = lane & 15, lgrp = lane >> 4;
  const u32 bid = blockIdx.x % 3125u;

  const u16* abase = xbf + (size_t)bid * 16384 + l15 * 32 + lgrp * 8;
  const u16* bbase = wws + (wcol * 80 + l15) * 32 + lgrp * 8;

  bf16x8 a0 = *(const bf16x8*)(abase);
  bf16x8 a1 = *(const bf16x8*)(abase + 512);
  bf16x8 b[5];
  #pragma unroll
  for (int n = 0; n < 5; ++n) b[n] = *(const bf16x8*)(bbase + n * 512);

  f32x4 acc[2][5];
  #pragma unroll
  for (int m = 0; m < 2; ++m)
    #pragma unroll
    for (int n = 0; n < 5; ++n)
      acc[m][n] = (f32x4){0.f, 0.f, 0.f, 0.f};

  #pragma unroll
  for (int kc = 0; kc < 16; ++kc) {
    #pragma unroll
    for (int n = 0; n < 5; ++n) {
      acc[0][n] = __builtin_amdgcn_mfma_f32_16x16x32_bf16(a0, b[n], acc[0][n], 0, 0, 0);
      acc[1][n] = __builtin_amdgcn_mfma_f32_16x16x32_bf16(a1, b[n], acc[1][n], 0, 0, 0);
    }
  }
  float s = 0.f;
  #pragma unroll
  for (int m = 0; m < 2; ++m)
    #pragma unroll
    for (int n = 0; n < 5; ++n)
      s += acc[m][n][0] + acc[m][n][1] + acc[m][n][2] + acc[m][n][3];
  ring[(blockIdx.x * 256 + tid) & 16383] = s;
}

// ---- k_p_full: full phase 1 (loads + MFMA + epilogue->LDS), NO phase 2 ----
__global__ __launch_bounds__(256, 4) void k_p_full(
    const u16* __restrict__ xbf, const u16* __restrict__ wws,
    const float* __restrict__ fc1b, const float* __restrict__ xencb,
    float* __restrict__ ring)
{
  __shared__ __align__(16) u16 sOut[32 * RH_LD];
  const int tid  = threadIdx.x;
  const int lane = tid & 63;
  const int wcol = tid >> 6;
  const int l15 = lane & 15, lgrp = lane >> 4;
  const u32 bid = blockIdx.x % 3125u;

  const u16* abase = xbf + (size_t)bid * 16384 + l15 * 32 + lgrp * 8;
  const u16* bbase = wws + (wcol * 80 + l15) * 32 + lgrp * 8;

  f32x4 acc[2][5];
  #pragma unroll
  for (int m = 0; m < 2; ++m)
    #pragma unroll
    for (int n = 0; n < 5; ++n)
      acc[m][n] = (f32x4){0.f, 0.f, 0.f, 0.f};

#define LAD(A0, A1, kc)                                                        \
  {                                                                            \
    A0 = *(const bf16x8*)(abase + (kc) * 1024);                                \
    A1 = *(const bf16x8*)(abase + (kc) * 1024 + 512);                          \
  }
#define LB(dst, kc)                                                            \
  {                                                                            \
    const u16* bp = bbase + (size_t)(kc) * (BN * 32);                          \
    _Pragma("unroll")                                                          \
    for (int n = 0; n < 5; ++n) dst[n] = *(const bf16x8*)(bp + n * 512);       \
  }
#define GS(kc, AC0, AC1, AN0, AN1, BU, BL)                                     \
  {                                                                            \
    if ((kc) < 15) { LAD(AN0, AN1, (kc) + 1); LB(BL, (kc) + 1); }              \
    _Pragma("unroll")                                                          \
    for (int n = 0; n < 5; ++n) {                                              \
      acc[0][n] = __builtin_amdgcn_mfma_f32_16x16x32_bf16(AC0, BU[n], acc[0][n], 0, 0, 0); \
      acc[1][n] = __builtin_amdgcn_mfma_f32_16x16x32_bf16(AC1, BU[n], acc[1][n], 0, 0, 0); \
    }                                                                          \
  }

  bf16x8 aX0, aX1, aY0, aY1, bP[5], bQ[5];
  LAD(aX0, aX1, 0); LB(bP, 0);
  GS(0,  aX0, aX1, aY0, aY1, bP, bQ)  GS(1,  aY0, aY1, aX0, aX1, bQ, bP)
  GS(2,  aX0, aX1, aY0, aY1, bP, bQ)  GS(3,  aY0, aY1, aX0, aX1, bQ, bP)
  GS(4,  aX0, aX1, aY0, aY1, bP, bQ)  GS(5,  aY0, aY1, aX0, aX1, bQ, bP)
  GS(6,  aX0, aX1, aY0, aY1, bP, bQ)  GS(7,  aY0, aY1, aX0, aX1, bQ, bP)
  GS(8,  aX0, aX1, aY0, aY1, bP, bQ)  GS(9,  aY0, aY1, aX0, aX1, bQ, bP)
  GS(10, aX0, aX1, aY0, aY1, bP, bQ)  GS(11, aY0, aY1, aX0, aX1, bQ, bP)
  GS(12, aX0, aX1, aY0, aY1, bP, bQ)  GS(13, aY0, aY1, aX0, aX1, bQ, bP)
  GS(14, aX0, aX1, aY0, aY1, bP, bQ)  GS(15, aY0, aY1, aX0, aX1, bQ, bP)
#undef LAD
#undef LB
#undef GS

  epilogue_store(sOut, acc, fc1b, xencb, wcol, l15, lgrp);
  __syncthreads();
  // keep LDS contents observable -> no DCE of epilogue
  ring[(blockIdx.x * 256 + tid) & 16383] = bf2f(sOut[(tid * 41) & 8191]);
}

// ---------------- Kernel 3: edge scores ----------------
__global__ __launch_bounds__(256) void k_edges(
    const int* __restrict__ ei, const int* __restrict__ ein,
    const float* __restrict__ sq, const float* __restrict__ sk,
    const float* __restrict__ pb, float* __restrict__ out)
{
  const int e = blockIdx.x * 256 + threadIdx.x;
  if (e >= E_NUM) return;
  const float b = pb[0];
  const int a0 = ei[e],  a1 = ei[E_NUM + e];
  out[e] = sq[a0] + sk[a1] + b;
  const int c0 = ein[e], c1 = ein[E_NUM + e];
  out[E_NUM + e] = sq[c0] + sk[c1] + b;
}

// ---------------- fallback staged kernel (small ws) ----------------
__global__ __launch_bounds__(256, 4) void k_fused_s(
    const float* __restrict__ x, const u16* __restrict__ wws, const u16* __restrict__ wwsB,
    const float* __restrict__ fc1b, const float* __restrict__ xencb,
    const int* __restrict__ y, const void* __restrict__ tmask,
    const float* __restrict__ fc2b, const float* __restrict__ pw,
    const int* __restrict__ mask_flag,
    float* __restrict__ out_lp, float* __restrict__ sq_out, float* __restrict__ sk_out)
{
  __shared__ __align__(16) u16 smem[16384];
  u16* sOut = smem;

  const int tid  = threadIdx.x;
  const int lane = tid & 63;
  const int wcol = tid >> 6;
  const int l15 = lane & 15, lgrp = lane >> 4;
  const long rowbase = (long)blockIdx.x * 32;

  {
    f32x4 v0[4], v1[4];
    #pragma unroll
    for (int half = 0; half < 2; ++half) {
      #pragma unroll
      for (int i = 0; i < 4; ++i) {
        const int g = tid + 256 * (half * 4 + i);
        const int r = g >> 6, c = g & 63;
        const int k0 = c * 8;
        v0[i] = (f32x4){0.f, 0.f, 0.f, 0.f};
        v1[i] = v0[i];
        const float* p = x + (rowbase + r) * F_DIM + k0;
        if (k0 + 4 <= F_DIM) v0[i] = *(const f32x4*)p;
        if (k0 + 8 <= F_DIM) v1[i] = *(const f32x4*)(p + 4);
      }
      #pragma unroll
      for (int i = 0; i < 4; ++i) {
        const int g = tid + 256 * (half * 4 + i);
        const int r = g >> 6, c = g & 63;
        const int phys = c ^ (r & 7);
        u16x8 o;
        #pragma unroll
        for (int j = 0; j < 4; ++j) { o[j] = f2bf(v0[i][j]); o[4 + j] = f2bf(v1[i][j]); }
        *(u16x8*)(smem + r * 512 + phys * 8) = o;
      }
    }
  }

  f32x4 acc[2][5];
  #pragma unroll
  for (int m = 0; m < 2; ++m)
    #pragma unroll
    for (int n = 0; n < 5; ++n)
      acc[m][n] = (f32x4){0.f, 0.f, 0.f, 0.f};

  const u16* bbase = wws + (wcol * 80 + l15) * 32 + lgrp * 8;
  const int arow_off = l15 * 512;

#define LB(dst, kc)                                                            \
  {                                                                            \
    const u16* bp = bbase + (size_t)(kc) * (BN * 32);                          \
    _Pragma("unroll")                                                          \
    for (int n = 0; n < 5; ++n) dst[n] = *(const bf16x8*)(bp + n * 512);       \
  }
#define LDA(A0, A1, kc)                                                        \
  {                                                                            \
    const int phys = (((kc) * 4 + lgrp) ^ (l15 & 7)) * 8;                      \
    A0 = *(const bf16x8*)(smem + arow_off + phys);                             \
    A1 = *(const bf16x8*)(smem + arow_off + 16 * 512 + phys);                  \
  }
#define GS(kc, AC0, AC1, AN0, AN1, BU, BL)                                     \
  {                                                                            \
    if ((kc) < 15) { LDA(AN0, AN1, (kc) + 1); LB(BL, (kc) + 1); }              \
    _Pragma("unroll")                                                          \
    for (int n = 0; n < 5; ++n) {                                              \
      acc[0][n] = __builtin_amdgcn_mfma_f32_16x16x32_bf16(AC0, BU[n], acc[0][n], 0, 0, 0); \
      acc[1][n] = __builtin_amdgcn_mfma_f32_16x16x32_bf16(AC1, BU[n], acc[1][n], 0, 0, 0); \
    }                                                                          \
  }

  bf16x8 aX0, aX1, aY0, aY1, bP[5], bQ[5];
  __syncthreads();
  LDA(aX0, aX1, 0); LB(bP, 0);
  GS(0,  aX0, aX1, aY0, aY1, bP, bQ)  GS(1,  aY0, aY1, aX0, aX1, bQ, bP)
  GS(2,  aX0, aX1, aY0, aY1, bP, bQ)  GS(3,  aY0, aY1, aX0, aX1, bQ, bP)
  GS(4,  aX0, aX1, aY0, aY1, bP, bQ)  GS(5,  aY0, aY1, aX0, aX1, bQ, bP)
  GS(6,  aX0, aX1, aY0, aY1, bP, bQ)  GS(7,  aY0, aY1, aX0, aX1, bQ, bP)
  GS(8,  aX0, aX1, aY0, aY1, bP, bQ)  GS(9,  aY0, aY1, aX0, aX1, bQ, bP)
  GS(10, aX0, aX1, aY0, aY1, bP, bQ)  GS(11, aY0, aY1, aX0, aX1, bQ, bP)
  GS(12, aX0, aX1, aY0, aY1, bP, bQ)  GS(13, aY0, aY1, aX0, aX1, bQ, bP)
  GS(14, aX0, aX1, aY0, aY1, bP, bQ)  GS(15, aY0, aY1, aX0, aX1, bQ, bP)
#undef LB
#undef LDA
#undef GS

  __syncthreads();
  epilogue_store(sOut, acc, fc1b, xencb, wcol, l15, lgrp);
  __syncthreads();
  rowhead_phase2(sOut, wwsB, y, tmask, fc2b, pw, (*mask_flag != 0), rowbase, tid,
                 out_lp, sq_out, sk_out);
}

extern "C" void kernel_launch(void* const* d_in, const int* in_sizes, int n_in,
                              void* d_out, int out_size, void* d_ws, size_t ws_size,
                              hipStream_t stream)
{
  const float* x     = (const float*)d_in[0];
  const int*   y     = (const int*)d_in[1];
  const void*  tm    = d_in[2];
  const int*   ei    = (const int*)d_in[3];
  const int*   ein   = (const int*)d_in[4];
  const float* fc1w  = (const float*)d_in[5];
  const float* fc1b  = (const float*)d_in[6];
  const float* fc2w  = (const float*)d_in[7];
  const float* fc2b  = (const float*)d_in[8];
  const float* xencw = (const float*)d_in[9];
  const float* xencb = (const float*)d_in[10];
  const float* pw    = (const float*)d_in[11];
  const float* pb    = (const float*)d_in[12];
  float* out = (float*)d_out;

  const bool big = (ws_size >= (size_t)103600000 + 65536);

  if (big) {
    u16*   xbf  = (u16*)d_ws;
    float* sq   = (float*)((char*)d_ws + 102400000);
    float* sk   = (float*)((char*)d_ws + 102800000);
    int*   flag = (int*)((char*)d_ws + 103200000);
    u16*   wws  = (u16*)((char*)d_ws + 103210000);
    u16*   wwsB = (u16*)((char*)d_ws + 103540000);
    float* ring = (float*)((char*)d_ws + 103580000);   // 64 KB, write-only

    k_detect <<<1, 256, 0, stream>>>((const u32*)tm, flag);
    k_cvtw   <<<80, 256, 0, stream>>>(fc1w, xencw, wws);
    k_cvtw2  <<<8, 256, 0, stream>>>(fc2w, pw, wwsB);
    k_cvtx   <<<N_NODES / 32, 256, 0, stream>>>(x, xbf);
    k_fused_d<<<N_NODES / 32, 256, 0, stream>>>(xbf, wws, wwsB, fc1b, xencb, y, tm,
                                                fc2b, pw, flag,
                                                out + 2 * (size_t)E_NUM, sq, sk);
    k_edges  <<<E_NUM / 256, 256, 0, stream>>>(ei, ein, sq, sk, pb, out);

    // decomposition probes, 4x amplified (clones via bid%3125)
    k_p_mf  <<<4 * (N_NODES / 32), 256, 0, stream>>>(xbf, wws, ring);
    k_p_ld  <<<4 * (N_NODES / 32), 256, 0, stream>>>(xbf, wws, ring);
    k_p_full<<<4 * (N_NODES / 32), 256, 0, stream>>>(xbf, wws, fc1b, xencb, ring);
  } else {
    float* sq   = (float*)((char*)d_ws + (size_t)N_NODES * O_DIM * 2);
    float* sk   = sq + N_NODES;
    int*   flag = (int*)(sk + N_NODES);
    u16*   wws  = (u16*)((char*)d_ws + 64800064);
    u16*   wwsB = (u16*)((char*)d_ws + 65127744);

    k_detect <<<1, 256, 0, stream>>>((const u32*)tm, flag);
    k_cvtw   <<<80, 256, 0, stream>>>(fc1w, xencw, wws);
    k_cvtw2  <<<8, 256, 0, stream>>>(fc2w, pw, wwsB);
    k_fused_s<<<N_NODES / 32, 256, 0, stream>>>(x, wws, wwsB, fc1b, xencb, y, tm,
                                                fc2b, pw, flag,
                                                out + 2 * (size_t)E_NUM, sq, sk);
    k_edges  <<<E_NUM / 256, 256, 0, stream>>>(ei, ein, sq, sk, pb, out);
  }
}

// Round 17
// 157.900 us; speedup vs baseline: 7.3419x; 7.3419x over previous
//
#include <hip/hip_runtime.h>
#include <stdint.h>

#define N_NODES 100000
#define F_DIM   500
#define C_DIM   40
#define H_DIM   256
#define HX_DIM  64
#define O_DIM   320   // H + HX
#define E_NUM   1600000
#define RH_LD   328
#define BN      320

typedef unsigned short u16;
typedef unsigned int   u32;
typedef __attribute__((ext_vector_type(4))) u16    u16x4;
typedef __attribute__((ext_vector_type(8))) u16    u16x8;
typedef __attribute__((ext_vector_type(4))) float  f32x4;
typedef __attribute__((ext_vector_type(8))) short  bf16x8;  // MFMA A/B frag

__device__ __forceinline__ float bf2f(u16 v) {
  u32 u = ((u32)v) << 16;
  return __builtin_bit_cast(float, u);
}
__device__ __forceinline__ u16 f2bf(float f) {   // round-to-nearest-even
  u32 x = __builtin_bit_cast(u32, f);
  x += 0x7fffu + ((x >> 16) & 1u);
  return (u16)(x >> 16);
}

// ---------------- Kernel 0: train_mask encoding detector ----------------
__global__ __launch_bounds__(256) void k_detect(const u32* __restrict__ tm, int* __restrict__ flag)
{
  __shared__ int s;
  if (threadIdx.x == 0) s = 0;
  __syncthreads();
  int local = 0;
  #pragma unroll
  for (int j = 0; j < 16; ++j) {
    if (tm[j * 256 + threadIdx.x] > 1u) local = 1;
  }
  if (local) s = 1;
  __syncthreads();
  if (threadIdx.x == 0) *flag = s;
}

// ---------------- Kernel 0b: W=[fc1_w;xenc_w] -> bf16, K-chunked frag layout ----------------
// wws[c*10240 + r*32 + s*8 + j] = bf16(W[r][c*32+s*8+j]), ZERO-PADDED past K=500
// (the zero pad makes the A-side K-tail clamp harmless in k_fused).
__global__ __launch_bounds__(256) void k_cvtw(
    const float* __restrict__ fc1w, const float* __restrict__ xencw, u16* __restrict__ wws)
{
  const int g = blockIdx.x * 256 + threadIdx.x;   // 20480 groups
  const int c = g / 1280;
  const int rem = g - c * 1280;
  const int r = rem >> 2;
  const int k0 = c * 32 + (rem & 3) * 8;
  const float* src = (r < H_DIM) ? (fc1w + (long)r * F_DIM)
                                 : (xencw + (long)(r - H_DIM) * F_DIM);
  f32x4 v0 = {0.f, 0.f, 0.f, 0.f}, v1 = v0;
  if (k0 + 4 <= F_DIM) v0 = *(const f32x4*)(src + k0);
  if (k0 + 8 <= F_DIM) v1 = *(const f32x4*)(src + k0 + 4);
  u16x8 o;
  #pragma unroll
  for (int i = 0; i < 4; ++i) { o[i] = f2bf(v0[i]); o[4 + i] = f2bf(v1[i]); }
  *(u16x8*)(wws + (size_t)g * 8) = o;
}

// ---------------- Kernel 0c: B' (48 x 320) -> bf16 K-chunked frag layout ----------------
__global__ __launch_bounds__(256) void k_cvtw2(
    const float* __restrict__ fc2w, const float* __restrict__ pw, u16* __restrict__ wwsB)
{
  const int g = blockIdx.x * 256 + threadIdx.x;   // 1920 groups
  if (g >= 1920) return;
  const int kc = g / 192;
  const int rem = g - kc * 192;
  const int r = rem >> 2;
  const int k0 = kc * 32 + (rem & 3) * 8;
  const float* src = nullptr;
  if (r < C_DIM)           { if (k0 + 8 <= H_DIM) src = fc2w + r * H_DIM + k0; }
  else if (r == C_DIM)     { if (k0 >= H_DIM) src = pw + (k0 - H_DIM); }
  else if (r == C_DIM + 1) { if (k0 >= H_DIM) src = pw + HX_DIM + (k0 - H_DIM); }
  u16x8 o = {0, 0, 0, 0, 0, 0, 0, 0};
  if (src) {
    const f32x4 v0 = *(const f32x4*)src;
    const f32x4 v1 = *(const f32x4*)(src + 4);
    #pragma unroll
    for (int i = 0; i < 4; ++i) { o[i] = f2bf(v0[i]); o[4 + i] = f2bf(v1[i]); }
  }
  *(u16x8*)(wwsB + (size_t)g * 8) = o;
}

// ---------------- shared phase-2 pieces (validated r4-r16 math) ----------------
__device__ __forceinline__ void epilogue_store(
    u16* sOut, f32x4 (&acc)[2][5], const float* __restrict__ fc1b,
    const float* __restrict__ xencb, int wcol, int l15, int lgrp)
{
  #pragma unroll
  for (int n = 0; n < 5; ++n) {
    const int col = wcol * 80 + n * 16 + l15;
    const float bias = (col < H_DIM) ? fc1b[col] : xencb[col - H_DIM];
    #pragma unroll
    for (int m = 0; m < 2; ++m) {
      const int r0 = m * 16 + lgrp * 4;
      #pragma unroll
      for (int rg = 0; rg < 4; ++rg)
        sOut[(r0 + rg) * RH_LD + col] = f2bf(fmaxf(acc[m][n][rg] + bias, 0.f));
    }
  }
}

__device__ __forceinline__ void rowhead_phase2(
    const u16* __restrict__ sOut, const u16* __restrict__ wwsB,
    const int* __restrict__ y, const void* __restrict__ tmask,
    const float* __restrict__ fc2b, const float* __restrict__ pw,
    bool byte_mask, long rowbase, int tid,
    float* __restrict__ out_lp, float* __restrict__ sq_out, float* __restrict__ sk_out)
{
  if (tid >= 128) return;
  const int lane = tid & 63, wid = tid >> 6;   // 0..1
  const int l15 = lane & 15, lgrp = lane >> 4;
  const u16* bBase = wwsB + l15 * 32 + lgrp * 8;
  f32x4 racc[3];
  #pragma unroll
  for (int n = 0; n < 3; ++n) racc[n] = (f32x4){0.f, 0.f, 0.f, 0.f};
  const u16* pa = sOut + (wid * 16 + l15) * RH_LD + lgrp * 8;

  bf16x8 bc[3], bn[3];
  #pragma unroll
  for (int n = 0; n < 3; ++n) bc[n] = *(const bf16x8*)(bBase + n * 512);

#define RH(kc, BC, BN_)                                                        \
  {                                                                            \
    if ((kc) < 9) {                                                            \
      _Pragma("unroll")                                                        \
      for (int n = 0; n < 3; ++n)                                              \
        BN_[n] = *(const bf16x8*)(bBase + ((kc) + 1) * 1536 + n * 512);        \
    }                                                                          \
    const bf16x8 a = *(const bf16x8*)(pa + (kc) * 32);                         \
    _Pragma("unroll")                                                          \
    for (int n = 0; n < 3; ++n)                                                \
      racc[n] = __builtin_amdgcn_mfma_f32_16x16x32_bf16(a, BC[n], racc[n], 0, 0, 0); \
  }
  RH(0, bc, bn) RH(1, bn, bc) RH(2, bc, bn) RH(3, bn, bc) RH(4, bc, bn)
  RH(5, bn, bc) RH(6, bc, bn) RH(7, bn, bc) RH(8, bc, bn) RH(9, bn, bc)
#undef RH

  const int c0 = l15, c1 = 16 + l15, c2 = 32 + l15;
  const bool v2 = (l15 < 8);
  const float b0 = fc2b[c0], b1 = fc2b[c1], b2 = v2 ? fc2b[c2] : 0.f;
  const float wq0 = pw[2 * HX_DIM + c0], wq1 = pw[2 * HX_DIM + c1],
              wq2 = v2 ? pw[2 * HX_DIM + c2] : 0.f;
  const float wk0 = pw[2 * HX_DIM + C_DIM + c0], wk1 = pw[2 * HX_DIM + C_DIM + c1],
              wk2 = v2 ? pw[2 * HX_DIM + C_DIM + c2] : 0.f;

  #pragma unroll
  for (int rg = 0; rg < 4; ++rg) {
    const long row = rowbase + wid * 16 + lgrp * 4 + rg;
    const float lg0 = racc[0][rg] + b0;
    const float lg1 = racc[1][rg] + b1;
    const float lg2 = racc[2][rg] + b2;
    const float sxq = __shfl(racc[2][rg], (lane & 48) | 8, 64);   // col 40: xe.w_xq
    const float sxk = __shfl(racc[2][rg], (lane & 48) | 9, 64);   // col 41: xe.w_xk

    float m = fmaxf(lg0, lg1);
    if (v2) m = fmaxf(m, lg2);
    #pragma unroll
    for (int off = 1; off < 16; off <<= 1) m = fmaxf(m, __shfl_xor(m, off, 64));
    const float e0 = __expf(lg0 - m), e1 = __expf(lg1 - m),
                e2 = v2 ? __expf(lg2 - m) : 0.f;
    float s = e0 + e1 + e2;
    #pragma unroll
    for (int off = 1; off < 16; off <<= 1) s += __shfl_xor(s, off, 64);
    const float lse = m + __logf(s);
    const float inv = 1.f / s;

    const int yv = y[row];
    const bool tm = byte_mask ? (((const unsigned char*)tmask)[row] != 0)
                              : (((const int*)tmask)[row] != 0);
    const float p0 = tm ? (c0 == yv ? 1.f : 0.f) : e0 * inv;
    const float p1 = tm ? (c1 == yv ? 1.f : 0.f) : e1 * inv;
    const float p2 = tm ? (c2 == yv ? 1.f : 0.f) : e2 * inv;
    float sq = p0 * wq0 + p1 * wq1 + p2 * wq2;
    float sk = p0 * wk0 + p1 * wk1 + p2 * wk2;
    #pragma unroll
    for (int off = 1; off < 16; off <<= 1) {
      sq += __shfl_xor(sq, off, 64);
      sk += __shfl_xor(sk, off, 64);
    }

    float* lp = out_lp + row * C_DIM;
    lp[c0] = lg0 - lse;
    lp[c1] = lg1 - lse;
    if (v2) lp[c2] = lg2 - lse;
    if (l15 == 0) { sq_out[row] = sq + sxq; sk_out[row] = sk + sxk; }
  }
}

// ---------------- Kernel 1: FUSED, direct f32-A (cvtx eliminated) ----------------
// A-frags load straight from x (f32, clamped K-tail: positions >= 500 multiply
// wws's zero pad -> garbage harmless; clamp keeps all addresses in-bounds).
// In-register RNE cvt. B-frags direct from L2-resident wws (validated layout).
__global__ __launch_bounds__(256, 4) void k_fused(
    const float* __restrict__ x, const u16* __restrict__ wws, const u16* __restrict__ wwsB,
    const float* __restrict__ fc1b, const float* __restrict__ xencb,
    const int* __restrict__ y, const void* __restrict__ tmask,
    const float* __restrict__ fc2b, const float* __restrict__ pw,
    const int* __restrict__ mask_flag,
    float* __restrict__ out_lp, float* __restrict__ sq_out, float* __restrict__ sk_out)
{
  __shared__ __align__(16) u16 sOut[32 * RH_LD];   // 21 KB, phase-2 only

  const int tid  = threadIdx.x;
  const int lane = tid & 63;
  const int wcol = tid >> 6;                // col strip (0..3)
  const int l15 = lane & 15, lgrp = lane >> 4;
  const long rowbase = (long)blockIdx.x * 32;

  // per-lane A rows (always valid: 3125*32 == 100000)
  const float* xrow0 = x + (rowbase + l15) * F_DIM;
  const float* xrow1 = xrow0 + 16 * F_DIM;
  // B frag base (validated layout: contiguous 1KB per wave-frag)
  const u16* bbase = wws + (wcol * 80 + l15) * 32 + lgrp * 8;

  f32x4 acc[2][5];
  #pragma unroll
  for (int m = 0; m < 2; ++m)
    #pragma unroll
    for (int n = 0; n < 5; ++n)
      acc[m][n] = (f32x4){0.f, 0.f, 0.f, 0.f};

// LA: load 4 x f32x4 (clamped <=496 keeps in-bounds; frag positions >= 500
// correspond to wws zero rows) and convert to two bf16x8 frags.
#define LA(AF0, AF1, kc)                                                       \
  {                                                                            \
    const int k0 = (kc) * 32 + lgrp * 8;                                       \
    const int ka = (k0 > 496) ? 496 : k0;                                      \
    const int kb = (k0 + 4 > 496) ? 496 : (k0 + 4);                            \
    const f32x4 t0 = *(const f32x4*)(xrow0 + ka);                              \
    const f32x4 t1 = *(const f32x4*)(xrow0 + kb);                              \
    const f32x4 t2 = *(const f32x4*)(xrow1 + ka);                              \
    const f32x4 t3 = *(const f32x4*)(xrow1 + kb);                              \
    _Pragma("unroll")                                                          \
    for (int i = 0; i < 4; ++i) {                                              \
      AF0[i]     = (short)f2bf(t0[i]);  AF0[4 + i] = (short)f2bf(t1[i]);       \
      AF1[i]     = (short)f2bf(t2[i]);  AF1[4 + i] = (short)f2bf(t3[i]);       \
    }                                                                          \
  }
#define LB(dst, kc)                                                            \
  {                                                                            \
    const u16* bp = bbase + (size_t)(kc) * (BN * 32);                          \
    _Pragma("unroll")                                                          \
    for (int n = 0; n < 5; ++n) dst[n] = *(const bf16x8*)(bp + n * 512);       \
  }
#define GS(kc, AC0, AC1, AN0, AN1, BU, BL)                                     \
  {                                                                            \
    if ((kc) < 15) { LA(AN0, AN1, (kc) + 1); LB(BL, (kc) + 1); }               \
    _Pragma("unroll")                                                          \
    for (int n = 0; n < 5; ++n) {                                              \
      acc[0][n] = __builtin_amdgcn_mfma_f32_16x16x32_bf16(AC0, BU[n], acc[0][n], 0, 0, 0); \
      acc[1][n] = __builtin_amdgcn_mfma_f32_16x16x32_bf16(AC1, BU[n], acc[1][n], 0, 0, 0); \
    }                                                                          \
  }

  bf16x8 aX0, aX1, aY0, aY1, bP[5], bQ[5];
  LA(aX0, aX1, 0); LB(bP, 0);
  GS(0,  aX0, aX1, aY0, aY1, bP, bQ)  GS(1,  aY0, aY1, aX0, aX1, bQ, bP)
  GS(2,  aX0, aX1, aY0, aY1, bP, bQ)  GS(3,  aY0, aY1, aX0, aX1, bQ, bP)
  GS(4,  aX0, aX1, aY0, aY1, bP, bQ)  GS(5,  aY0, aY1, aX0, aX1, bQ, bP)
  GS(6,  aX0, aX1, aY0, aY1, bP, bQ)  GS(7,  aY0, aY1, aX0, aX1, bQ, bP)
  GS(8,  aX0, aX1, aY0, aY1, bP, bQ)  GS(9,  aY0, aY1, aX0, aX1, bQ, bP)
  GS(10, aX0, aX1, aY0, aY1, bP, bQ)  GS(11, aY0, aY1, aX0, aX1, bQ, bP)
  GS(12, aX0, aX1, aY0, aY1, bP, bQ)  GS(13, aY0, aY1, aX0, aX1, bQ, bP)
  GS(14, aX0, aX1, aY0, aY1, bP, bQ)  GS(15, aY0, aY1, aX0, aX1, bQ, bP)
#undef LA
#undef LB
#undef GS

  epilogue_store(sOut, acc, fc1b, xencb, wcol, l15, lgrp);
  __syncthreads();
  rowhead_phase2(sOut, wwsB, y, tmask, fc2b, pw, (*mask_flag != 0), rowbase, tid,
                 out_lp, sq_out, sk_out);
}

// ---------------- Kernel 3: edge scores ----------------
__global__ __launch_bounds__(256) void k_edges(
    const int* __restrict__ ei, const int* __restrict__ ein,
    const float* __restrict__ sq, const float* __restrict__ sk,
    const float* __restrict__ pb, float* __restrict__ out)
{
  const int e = blockIdx.x * 256 + threadIdx.x;
  if (e >= E_NUM) return;
  const float b = pb[0];
  const int a0 = ei[e],  a1 = ei[E_NUM + e];
  out[e] = sq[a0] + sk[a1] + b;
  const int c0 = ein[e], c1 = ein[E_NUM + e];
  out[E_NUM + e] = sq[c0] + sk[c1] + b;
}

extern "C" void kernel_launch(void* const* d_in, const int* in_sizes, int n_in,
                              void* d_out, int out_size, void* d_ws, size_t ws_size,
                              hipStream_t stream)
{
  const float* x     = (const float*)d_in[0];
  const int*   y     = (const int*)d_in[1];
  const void*  tm    = d_in[2];
  const int*   ei    = (const int*)d_in[3];
  const int*   ein   = (const int*)d_in[4];
  const float* fc1w  = (const float*)d_in[5];
  const float* fc1b  = (const float*)d_in[6];
  const float* fc2w  = (const float*)d_in[7];
  const float* fc2b  = (const float*)d_in[8];
  const float* xencw = (const float*)d_in[9];
  const float* xencb = (const float*)d_in[10];
  const float* pw    = (const float*)d_in[11];
  const float* pb    = (const float*)d_in[12];
  float* out = (float*)d_out;

  // ws: sq (400KB) | sk (400KB) | flag | wws (320KB) | wwsB (30KB)  -> ~1.2 MB
  float* sq   = (float*)d_ws;
  float* sk   = (float*)((char*)d_ws + 400000);
  int*   flag = (int*)((char*)d_ws + 800000);
  u16*   wws  = (u16*)((char*)d_ws + 800064);
  u16*   wwsB = (u16*)((char*)d_ws + 1127744);

  k_detect<<<1, 256, 0, stream>>>((const u32*)tm, flag);
  k_cvtw  <<<80, 256, 0, stream>>>(fc1w, xencw, wws);
  k_cvtw2 <<<8, 256, 0, stream>>>(fc2w, pw, wwsB);
  k_fused <<<N_NODES / 32, 256, 0, stream>>>(x, wws, wwsB, fc1b, xencb, y, tm,
                                             fc2b, pw, flag,
                                             out + 2 * (size_t)E_NUM, sq, sk);
  k_edges <<<E_NUM / 256, 256, 0, stream>>>(ei, ein, sq, sk, pb, out);
}

// Round 18
// 149.493 us; speedup vs baseline: 7.7548x; 1.0562x over previous
//
#include <hip/hip_runtime.h>
#include <stdint.h>

#define N_NODES 100000
#define F_DIM   500
#define C_DIM   40
#define H_DIM   256
#define HX_DIM  64
#define O_DIM   320   // H + HX
#define E_NUM   1600000
#define RH_LD   328
#define BN      320
#define G_BM    64

typedef unsigned short u16;
typedef unsigned int   u32;
typedef __attribute__((ext_vector_type(4))) u16    u16x4;
typedef __attribute__((ext_vector_type(8))) u16    u16x8;
typedef __attribute__((ext_vector_type(4))) float  f32x4;
typedef __attribute__((ext_vector_type(8))) short  bf16x8;  // MFMA A/B frag

__device__ __forceinline__ float bf2f(u16 v) {
  u32 u = ((u32)v) << 16;
  return __builtin_bit_cast(float, u);
}
__device__ __forceinline__ u16 f2bf(float f) {   // round-to-nearest-even
  u32 x = __builtin_bit_cast(u32, f);
  x += 0x7fffu + ((x >> 16) & 1u);
  return (u16)(x >> 16);
}

// ---------------- Kernel 0: train_mask encoding detector ----------------
__global__ __launch_bounds__(256) void k_detect(const u32* __restrict__ tm, int* __restrict__ flag)
{
  __shared__ int s;
  if (threadIdx.x == 0) s = 0;
  __syncthreads();
  int local = 0;
  #pragma unroll
  for (int j = 0; j < 16; ++j) {
    if (tm[j * 256 + threadIdx.x] > 1u) local = 1;
  }
  if (local) s = 1;
  __syncthreads();
  if (threadIdx.x == 0) *flag = s;
}

// ---------------- Kernel 0b: W=[fc1_w;xenc_w] -> bf16, K-chunked frag layout ----------------
// wws[c*10240 + r*32 + s*8 + j] = bf16(W[r][c*32+s*8+j]), ZERO-PADDED past K=500.
__global__ __launch_bounds__(256) void k_cvtw(
    const float* __restrict__ fc1w, const float* __restrict__ xencw, u16* __restrict__ wws)
{
  const int g = blockIdx.x * 256 + threadIdx.x;   // 20480 groups
  const int c = g / 1280;
  const int rem = g - c * 1280;
  const int r = rem >> 2;
  const int k0 = c * 32 + (rem & 3) * 8;
  const float* src = (r < H_DIM) ? (fc1w + (long)r * F_DIM)
                                 : (xencw + (long)(r - H_DIM) * F_DIM);
  f32x4 v0 = {0.f, 0.f, 0.f, 0.f}, v1 = v0;
  if (k0 + 4 <= F_DIM) v0 = *(const f32x4*)(src + k0);
  if (k0 + 8 <= F_DIM) v1 = *(const f32x4*)(src + k0 + 4);
  u16x8 o;
  #pragma unroll
  for (int i = 0; i < 4; ++i) { o[i] = f2bf(v0[i]); o[4 + i] = f2bf(v1[i]); }
  *(u16x8*)(wws + (size_t)g * 8) = o;
}

// ---------------- Kernel 0c: B' (48 x 320) -> bf16 K-chunked frag layout ----------------
__global__ __launch_bounds__(256) void k_cvtw2(
    const float* __restrict__ fc2w, const float* __restrict__ pw, u16* __restrict__ wwsB)
{
  const int g = blockIdx.x * 256 + threadIdx.x;   // 1920 groups
  if (g >= 1920) return;
  const int kc = g / 192;
  const int rem = g - kc * 192;
  const int r = rem >> 2;
  const int k0 = kc * 32 + (rem & 3) * 8;
  const float* src = nullptr;
  if (r < C_DIM)           { if (k0 + 8 <= H_DIM) src = fc2w + r * H_DIM + k0; }
  else if (r == C_DIM)     { if (k0 >= H_DIM) src = pw + (k0 - H_DIM); }
  else if (r == C_DIM + 1) { if (k0 >= H_DIM) src = pw + HX_DIM + (k0 - H_DIM); }
  u16x8 o = {0, 0, 0, 0, 0, 0, 0, 0};
  if (src) {
    const f32x4 v0 = *(const f32x4*)src;
    const f32x4 v1 = *(const f32x4*)(src + 4);
    #pragma unroll
    for (int i = 0; i < 4; ++i) { o[i] = f2bf(v0[i]); o[4 + i] = f2bf(v1[i]); }
  }
  *(u16x8*)(wwsB + (size_t)g * 8) = o;
}

// ---------------- Kernel 1: FUSED, BM=64, acc[4][5]/wave (B reused x2) ----------------
// 256 thr = 4 waves; wave w = col strip (80 cols) x ALL 64 rows (4 row-frags).
// A direct-f32 (clamped tail), B direct from L2-resident wws. Phase 2: all 4 waves.
__global__ __launch_bounds__(256, 2) void k_fused(
    const float* __restrict__ x, const u16* __restrict__ wws, const u16* __restrict__ wwsB,
    const float* __restrict__ fc1b, const float* __restrict__ xencb,
    const int* __restrict__ y, const void* __restrict__ tmask,
    const float* __restrict__ fc2b, const float* __restrict__ pw,
    const int* __restrict__ mask_flag,
    float* __restrict__ out_lp, float* __restrict__ sq_out, float* __restrict__ sk_out)
{
  __shared__ __align__(16) u16 sOut[G_BM * RH_LD];   // 42 KB, phase-2 only

  const int tid  = threadIdx.x;
  const int lane = tid & 63;
  const int wcol = tid >> 6;                // col strip (0..3)
  const int l15 = lane & 15, lgrp = lane >> 4;
  const long rowbase = (long)blockIdx.x * G_BM;   // 1563 blocks; last is partial

  // per-lane A row pointers for the 4 row-frags (clamped; garbage rows never stored)
  long rr0 = rowbase + l15,      rr1 = rr0 + 16, rr2 = rr0 + 32, rr3 = rr0 + 48;
  if (rr0 > N_NODES - 1) rr0 = N_NODES - 1;
  if (rr1 > N_NODES - 1) rr1 = N_NODES - 1;
  if (rr2 > N_NODES - 1) rr2 = N_NODES - 1;
  if (rr3 > N_NODES - 1) rr3 = N_NODES - 1;
  const float* xp0 = x + rr0 * F_DIM;
  const float* xp1 = x + rr1 * F_DIM;
  const float* xp2 = x + rr2 * F_DIM;
  const float* xp3 = x + rr3 * F_DIM;

  const u16* bbase = wws + (wcol * 80 + l15) * 32 + lgrp * 8;

  f32x4 acc[4][5];
  #pragma unroll
  for (int m = 0; m < 4; ++m)
    #pragma unroll
    for (int n = 0; n < 5; ++n)
      acc[m][n] = (f32x4){0.f, 0.f, 0.f, 0.f};

// LA: 8 f32x4 loads (4 rows x 2 halves, clamped K-tail: positions >= 500 hit
// wws zero rows) -> 4 bf16x8 frags.
#define LA(F0, F1, F2, F3, kc)                                                 \
  {                                                                            \
    const int k0 = (kc) * 32 + lgrp * 8;                                       \
    const int ka = (k0 > 496) ? 496 : k0;                                      \
    const int kb = (k0 + 4 > 496) ? 496 : (k0 + 4);                            \
    const f32x4 u0 = *(const f32x4*)(xp0 + ka), w0 = *(const f32x4*)(xp0 + kb);\
    const f32x4 u1 = *(const f32x4*)(xp1 + ka), w1 = *(const f32x4*)(xp1 + kb);\
    const f32x4 u2 = *(const f32x4*)(xp2 + ka), w2 = *(const f32x4*)(xp2 + kb);\
    const f32x4 u3 = *(const f32x4*)(xp3 + ka), w3 = *(const f32x4*)(xp3 + kb);\
    _Pragma("unroll")                                                          \
    for (int i = 0; i < 4; ++i) {                                              \
      F0[i] = (short)f2bf(u0[i]);  F0[4 + i] = (short)f2bf(w0[i]);             \
      F1[i] = (short)f2bf(u1[i]);  F1[4 + i] = (short)f2bf(w1[i]);             \
      F2[i] = (short)f2bf(u2[i]);  F2[4 + i] = (short)f2bf(w2[i]);             \
      F3[i] = (short)f2bf(u3[i]);  F3[4 + i] = (short)f2bf(w3[i]);             \
    }                                                                          \
  }
#define LB(dst, kc)                                                            \
  {                                                                            \
    const u16* bp = bbase + (size_t)(kc) * (BN * 32);                          \
    _Pragma("unroll")                                                          \
    for (int n = 0; n < 5; ++n) dst[n] = *(const bf16x8*)(bp + n * 512);       \
  }
// GS: prefetch next A/B, then 20 MFMAs (4 row-frags x 5 col-frags).
#define GS(kc, AC0, AC1, AC2, AC3, AN0, AN1, AN2, AN3, BU, BL)                 \
  {                                                                            \
    if ((kc) < 15) { LA(AN0, AN1, AN2, AN3, (kc) + 1); LB(BL, (kc) + 1); }     \
    _Pragma("unroll")                                                          \
    for (int n = 0; n < 5; ++n) {                                              \
      acc[0][n] = __builtin_amdgcn_mfma_f32_16x16x32_bf16(AC0, BU[n], acc[0][n], 0, 0, 0); \
      acc[1][n] = __builtin_amdgcn_mfma_f32_16x16x32_bf16(AC1, BU[n], acc[1][n], 0, 0, 0); \
      acc[2][n] = __builtin_amdgcn_mfma_f32_16x16x32_bf16(AC2, BU[n], acc[2][n], 0, 0, 0); \
      acc[3][n] = __builtin_amdgcn_mfma_f32_16x16x32_bf16(AC3, BU[n], acc[3][n], 0, 0, 0); \
    }                                                                          \
  }

  bf16x8 aX0, aX1, aX2, aX3, aY0, aY1, aY2, aY3, bP[5], bQ[5];
  LA(aX0, aX1, aX2, aX3, 0); LB(bP, 0);
  GS(0,  aX0, aX1, aX2, aX3, aY0, aY1, aY2, aY3, bP, bQ)
  GS(1,  aY0, aY1, aY2, aY3, aX0, aX1, aX2, aX3, bQ, bP)
  GS(2,  aX0, aX1, aX2, aX3, aY0, aY1, aY2, aY3, bP, bQ)
  GS(3,  aY0, aY1, aY2, aY3, aX0, aX1, aX2, aX3, bQ, bP)
  GS(4,  aX0, aX1, aX2, aX3, aY0, aY1, aY2, aY3, bP, bQ)
  GS(5,  aY0, aY1, aY2, aY3, aX0, aX1, aX2, aX3, bQ, bP)
  GS(6,  aX0, aX1, aX2, aX3, aY0, aY1, aY2, aY3, bP, bQ)
  GS(7,  aY0, aY1, aY2, aY3, aX0, aX1, aX2, aX3, bQ, bP)
  GS(8,  aX0, aX1, aX2, aX3, aY0, aY1, aY2, aY3, bP, bQ)
  GS(9,  aY0, aY1, aY2, aY3, aX0, aX1, aX2, aX3, bQ, bP)
  GS(10, aX0, aX1, aX2, aX3, aY0, aY1, aY2, aY3, bP, bQ)
  GS(11, aY0, aY1, aY2, aY3, aX0, aX1, aX2, aX3, bQ, bP)
  GS(12, aX0, aX1, aX2, aX3, aY0, aY1, aY2, aY3, bP, bQ)
  GS(13, aY0, aY1, aY2, aY3, aX0, aX1, aX2, aX3, bQ, bP)
  GS(14, aX0, aX1, aX2, aX3, aY0, aY1, aY2, aY3, bP, bQ)
  GS(15, aY0, aY1, aY2, aY3, aX0, aX1, aX2, aX3, bQ, bP)
#undef LA
#undef LB
#undef GS

  // ---- epilogue: bias+relu -> sOut [64][328] ----
  #pragma unroll
  for (int n = 0; n < 5; ++n) {
    const int col = wcol * 80 + n * 16 + l15;
    const float bias = (col < H_DIM) ? fc1b[col] : xencb[col - H_DIM];
    #pragma unroll
    for (int m = 0; m < 4; ++m) {
      const int r0 = m * 16 + lgrp * 4;
      #pragma unroll
      for (int rg = 0; rg < 4; ++rg)
        sOut[(r0 + rg) * RH_LD + col] = f2bf(fmaxf(acc[m][n][rg] + bias, 0.f));
    }
  }
  __syncthreads();

  // ---- phase 2: rowhead, ALL 4 waves (16 rows each), validated r4-r17 math ----
  {
    const int wid = tid >> 6;                      // 0..3
    const u16* bBase = wwsB + l15 * 32 + lgrp * 8;
    f32x4 racc[3];
    #pragma unroll
    for (int n = 0; n < 3; ++n) racc[n] = (f32x4){0.f, 0.f, 0.f, 0.f};
    const u16* pa = sOut + (wid * 16 + l15) * RH_LD + lgrp * 8;

    bf16x8 bc[3], bn[3];
    #pragma unroll
    for (int n = 0; n < 3; ++n) bc[n] = *(const bf16x8*)(bBase + n * 512);

#define RH(kc, BC, BN_)                                                        \
    {                                                                          \
      if ((kc) < 9) {                                                          \
        _Pragma("unroll")                                                      \
        for (int n = 0; n < 3; ++n)                                            \
          BN_[n] = *(const bf16x8*)(bBase + ((kc) + 1) * 1536 + n * 512);      \
      }                                                                        \
      const bf16x8 a = *(const bf16x8*)(pa + (kc) * 32);                       \
      _Pragma("unroll")                                                        \
      for (int n = 0; n < 3; ++n)                                              \
        racc[n] = __builtin_amdgcn_mfma_f32_16x16x32_bf16(a, BC[n], racc[n], 0, 0, 0); \
    }
    RH(0, bc, bn) RH(1, bn, bc) RH(2, bc, bn) RH(3, bn, bc) RH(4, bc, bn)
    RH(5, bn, bc) RH(6, bc, bn) RH(7, bn, bc) RH(8, bc, bn) RH(9, bn, bc)
#undef RH

    const int c0 = l15, c1 = 16 + l15, c2 = 32 + l15;
    const bool v2 = (l15 < 8);
    const float b0 = fc2b[c0], b1 = fc2b[c1], b2 = v2 ? fc2b[c2] : 0.f;
    const float wq0 = pw[2 * HX_DIM + c0], wq1 = pw[2 * HX_DIM + c1],
                wq2 = v2 ? pw[2 * HX_DIM + c2] : 0.f;
    const float wk0 = pw[2 * HX_DIM + C_DIM + c0], wk1 = pw[2 * HX_DIM + C_DIM + c1],
                wk2 = v2 ? pw[2 * HX_DIM + C_DIM + c2] : 0.f;
    const bool byte_mask = (*mask_flag != 0);

    #pragma unroll
    for (int rg = 0; rg < 4; ++rg) {
      const long row = rowbase + wid * 16 + lgrp * 4 + rg;
      const bool rv = (row < N_NODES);
      const long rowc = rv ? row : (N_NODES - 1);
      const float lg0 = racc[0][rg] + b0;
      const float lg1 = racc[1][rg] + b1;
      const float lg2 = racc[2][rg] + b2;
      const float sxq = __shfl(racc[2][rg], (lane & 48) | 8, 64);   // col 40: xe.w_xq
      const float sxk = __shfl(racc[2][rg], (lane & 48) | 9, 64);   // col 41: xe.w_xk

      float m = fmaxf(lg0, lg1);
      if (v2) m = fmaxf(m, lg2);
      #pragma unroll
      for (int off = 1; off < 16; off <<= 1) m = fmaxf(m, __shfl_xor(m, off, 64));
      const float e0 = __expf(lg0 - m), e1 = __expf(lg1 - m),
                  e2 = v2 ? __expf(lg2 - m) : 0.f;
      float s = e0 + e1 + e2;
      #pragma unroll
      for (int off = 1; off < 16; off <<= 1) s += __shfl_xor(s, off, 64);
      const float lse = m + __logf(s);
      const float inv = 1.f / s;

      const int yv = y[rowc];
      const bool tm = byte_mask ? (((const unsigned char*)tmask)[rowc] != 0)
                                : (((const int*)tmask)[rowc] != 0);
      const float p0 = tm ? (c0 == yv ? 1.f : 0.f) : e0 * inv;
      const float p1 = tm ? (c1 == yv ? 1.f : 0.f) : e1 * inv;
      const float p2 = tm ? (c2 == yv ? 1.f : 0.f) : e2 * inv;
      float sq = p0 * wq0 + p1 * wq1 + p2 * wq2;
      float sk = p0 * wk0 + p1 * wk1 + p2 * wk2;
      #pragma unroll
      for (int off = 1; off < 16; off <<= 1) {
        sq += __shfl_xor(sq, off, 64);
        sk += __shfl_xor(sk, off, 64);
      }

      if (rv) {
        float* lp = out_lp + row * C_DIM;
        lp[c0] = lg0 - lse;
        lp[c1] = lg1 - lse;
        if (v2) lp[c2] = lg2 - lse;
        if (l15 == 0) { sq_out[row] = sq + sxq; sk_out[row] = sk + sxk; }
      }
    }
  }
}

// ---------------- Kernel 3: edge scores ----------------
__global__ __launch_bounds__(256) void k_edges(
    const int* __restrict__ ei, const int* __restrict__ ein,
    const float* __restrict__ sq, const float* __restrict__ sk,
    const float* __restrict__ pb, float* __restrict__ out)
{
  const int e = blockIdx.x * 256 + threadIdx.x;
  if (e >= E_NUM) return;
  const float b = pb[0];
  const int a0 = ei[e],  a1 = ei[E_NUM + e];
  out[e] = sq[a0] + sk[a1] + b;
  const int c0 = ein[e], c1 = ein[E_NUM + e];
  out[E_NUM + e] = sq[c0] + sk[c1] + b;
}

extern "C" void kernel_launch(void* const* d_in, const int* in_sizes, int n_in,
                              void* d_out, int out_size, void* d_ws, size_t ws_size,
                              hipStream_t stream)
{
  const float* x     = (const float*)d_in[0];
  const int*   y     = (const int*)d_in[1];
  const void*  tm    = d_in[2];
  const int*   ei    = (const int*)d_in[3];
  const int*   ein   = (const int*)d_in[4];
  const float* fc1w  = (const float*)d_in[5];
  const float* fc1b  = (const float*)d_in[6];
  const float* fc2w  = (const float*)d_in[7];
  const float* fc2b  = (const float*)d_in[8];
  const float* xencw = (const float*)d_in[9];
  const float* xencb = (const float*)d_in[10];
  const float* pw    = (const float*)d_in[11];
  const float* pb    = (const float*)d_in[12];
  float* out = (float*)d_out;

  // ws: sq (400KB) | sk (400KB) | flag | wws (320KB) | wwsB (30KB)
  float* sq   = (float*)d_ws;
  float* sk   = (float*)((char*)d_ws + 400000);
  int*   flag = (int*)((char*)d_ws + 800000);
  u16*   wws  = (u16*)((char*)d_ws + 800064);
  u16*   wwsB = (u16*)((char*)d_ws + 1127744);

  k_detect<<<1, 256, 0, stream>>>((const u32*)tm, flag);
  k_cvtw  <<<80, 256, 0, stream>>>(fc1w, xencw, wws);
  k_cvtw2 <<<8, 256, 0, stream>>>(fc2w, pw, wwsB);
  const int nblk = (N_NODES + G_BM - 1) / G_BM;   // 1563
  k_fused <<<nblk, 256, 0, stream>>>(x, wws, wwsB, fc1b, xencb, y, tm,
                                     fc2b, pw, flag,
                                     out + 2 * (size_t)E_NUM, sq, sk);
  k_edges <<<E_NUM / 256, 256, 0, stream>>>(ei, ein, sq, sk, pb, out);
}